// Round 5
// baseline (235.540 us; speedup 1.0000x reference)
//
#include <hip/hip_runtime.h>

// DistanceCentroidLoss via bf16 MFMA, round 5: 12 waves/CU (GRID=768, 3 blocks/CU,
// __launch_bounds__(256,3)), c2 folded into MFMA accumulator init (-c2/2 tables),
// per-wave static 2-or-3-tile work list, labels prefetched.
// A=centroids (64 rows, 2 accumulators), B=points (32 cols/wave).
// d2 = x2 - 2*acc', acc' = dot - c2/2 (C initialized to -c2/2).
// C/D layout (32x32x16): col = lane&31 (point), row = (reg&3) + 8*(reg>>2) + 4*(lane>>5).
// Panel layout: point n's chunk c (bf16x4) at 8B-slot 34*n + c (writes/reads <=2-way, free).

constexpr int N = 262144;
constexpr int D = 128;
constexpr int K = 64;

constexpr int GRID = 768;                    // 3 blocks/CU exactly resident
constexpr int NWAVES = 4;                    // 256 threads/block
constexpr int NWTOT = GRID * NWAVES;         // 3072 waves
constexpr int NTILES = N / 32;               // 8192 tiles of 32 points
constexpr int PANEL = 34 * 32;               // bf16x4 slots per wave panel

typedef __bf16 bf16x4 __attribute__((ext_vector_type(4)));
typedef __bf16 bf16x8 __attribute__((ext_vector_type(8)));
typedef float  f32x16 __attribute__((ext_vector_type(16)));

__global__ __launch_bounds__(256, 3) void dcl_main(
    const float* __restrict__ emb,
    const int*   __restrict__ labels,
    const float* __restrict__ cent,
    float* __restrict__ g_attr,
    float* __restrict__ g_rep,
    int*   __restrict__ g_cnt)
{
    __shared__ bf16x8 sA[2 * 8 * 64];                       // 16 KB A-fragments
    __shared__ __align__(16) bf16x4 sPanel[NWAVES * PANEL]; // 34 KB transpose panels
    __shared__ float  s_c2[K];
    __shared__ __align__(16) float sC2i0[2][16];            // -c2/2, acc0 init, [h][r]
    __shared__ __align__(16) float sC2i1[2][16];            // -c2/2, acc1 init, [h][r]
    __shared__ float  s_attr[K];
    __shared__ float  s_rep[K];
    __shared__ int    s_cnt[K];

    const int tid  = threadIdx.x;
    const int wave = tid >> 6;
    const int lane = tid & 63;
    const int l31  = lane & 31;
    const int h    = lane >> 5;

    // --- per-wave static tile list: 2 base tiles + 1 extra for 2/3 of waves ---
    const int g = blockIdx.x * NWAVES + wave;   // 0..3071, wave-uniform
    int tiles[3];
    tiles[0] = g;
    tiles[1] = g + NWTOT;
    int nt = 2;
    if (g % 3 != 2) { tiles[2] = 2 * NWTOT + (g - g / 3); nt = 3; }

    // issue first tile's loads immediately (contiguous: lane strides 16 B, 1 KB/inst)
    float4 buf[16];
    {
        const float4* src = (const float4*)emb + (size_t)tiles[0] * 1024 + lane;
        #pragma unroll
        for (int q = 0; q < 16; ++q) buf[q] = src[q * 64];
    }
    // prefetch all labels this wave needs
    int lbl[3];
    lbl[0] = labels[tiles[0] * 32 + l31];
    lbl[1] = labels[tiles[1] * 32 + l31];
    lbl[2] = (nt == 3) ? labels[tiles[2] * 32 + l31] : 0;

    // --- stage centroid A-fragments into LDS (fragment order, 16B/lane) ---
    #pragma unroll
    for (int e = tid; e < 2 * 8 * 64; e += 256) {
        const int t = e >> 9, s = (e >> 6) & 7, l = e & 63;
        const int c  = t * 32 + (l & 31);
        const int d0 = 16 * s + 8 * (l >> 5);
        const float4 f0 = *(const float4*)(cent + c * D + d0);
        const float4 f1 = *(const float4*)(cent + c * D + d0 + 4);
        bf16x8 v;
        v[0] = (__bf16)f0.x; v[1] = (__bf16)f0.y; v[2] = (__bf16)f0.z; v[3] = (__bf16)f0.w;
        v[4] = (__bf16)f1.x; v[5] = (__bf16)f1.y; v[6] = (__bf16)f1.z; v[7] = (__bf16)f1.w;
        sA[e] = v;
    }
    if (tid < K) {
        const float4* cp = (const float4*)(cent + tid * D);
        float s = 0.f;
        #pragma unroll
        for (int q = 0; q < D / 4; ++q) {
            const float4 f = cp[q];
            s = fmaf(f.x, f.x, s); s = fmaf(f.y, f.y, s);
            s = fmaf(f.z, f.z, s); s = fmaf(f.w, f.w, s);
        }
        s_c2[tid] = s;
        s_attr[tid] = 0.f; s_rep[tid] = 0.f; s_cnt[tid] = 0;
    }
    __syncthreads();
    if (tid < 32) {
        const int hh = tid >> 4, r = tid & 15;
        const int rb = (r & 3) + 8 * (r >> 2) + 4 * hh;
        sC2i0[hh][r] = -0.5f * s_c2[rb];
        sC2i1[hh][r] = -0.5f * s_c2[rb + 32];
    }
    __syncthreads();

    bf16x4* panel = sPanel + wave * PANEL;

    for (int i = 0; i < nt; ++i) {
        // convert current tile to bf16 and transpose into the panel (wave-private)
        #pragma unroll
        for (int q = 0; q < 16; ++q) {
            bf16x4 v;
            v[0] = (__bf16)buf[q].x; v[1] = (__bf16)buf[q].y;
            v[2] = (__bf16)buf[q].z; v[3] = (__bf16)buf[q].w;
            const int n = 2 * q + h;        // point within tile
            panel[34 * n + l31] = v;        // chunk c = l31
        }

        // prefetch next tile's global loads before the MFMA phase
        if (i + 1 < nt) {
            const float4* src = (const float4*)emb + (size_t)tiles[i + 1] * 1024 + lane;
            #pragma unroll
            for (int q = 0; q < 16; ++q) buf[q] = src[q * 64];
        }

        // accumulators pre-initialized to -c2/2 (folds the c2 term into the GEMM)
        f32x16 acc0, acc1;
        {
            const float4* p0 = (const float4*)&sC2i0[h][0];
            const float4* p1 = (const float4*)&sC2i1[h][0];
            #pragma unroll
            for (int w = 0; w < 4; ++w) {
                ((float4*)&acc0)[w] = p0[w];
                ((float4*)&acc1)[w] = p1[w];
            }
        }
        float x2p = 0.f;

        #pragma unroll
        for (int s = 0; s < 8; ++s) {
            // lane's own point's dwords [16s+8h, 16s+8h+8) as bf16
            const bf16x8 b = *(const bf16x8*)&panel[34 * l31 + 4 * s + 2 * h];
            #pragma unroll
            for (int e = 0; e < 8; ++e) {
                const float fe = (float)b[e];
                x2p = fmaf(fe, fe, x2p);
            }
            const bf16x8 a0 = sA[s * 64 + lane];
            const bf16x8 a1 = sA[(8 + s) * 64 + lane];
            acc0 = __builtin_amdgcn_mfma_f32_32x32x16_bf16(a0, b, acc0, 0, 0, 0);
            acc1 = __builtin_amdgcn_mfma_f32_32x32x16_bf16(a1, b, acc1, 0, 0, 0);
        }

        const float x2 = x2p + __shfl_xor(x2p, 32);
        const int li = lbl[i];

        float s1 = 0.f, s2 = 0.f, own = 0.f;
        #pragma unroll
        for (int r = 0; r < 16; ++r) {
            const int rbase = (r & 3) + 8 * (r >> 2) + 4 * h;
            {
                float d2 = fmaf(-2.f, acc0[r], x2);
                d2 = fmaxf(d2, 0.f);
                const float dd = __builtin_amdgcn_sqrtf(d2);
                s1 += dd; s2 += d2;
                if (rbase == li) own += d2;
            }
            {
                float d2 = fmaf(-2.f, acc1[r], x2);
                d2 = fmaxf(d2, 0.f);
                const float dd = __builtin_amdgcn_sqrtf(d2);
                s1 += dd; s2 += d2;
                if (rbase + 32 == li) own += d2;
            }
        }
        s1  += __shfl_xor(s1, 32);
        s2  += __shfl_xor(s2, 32);
        own += __shfl_xor(own, 32);

        if (lane < 32) {
            const float down = __builtin_amdgcn_sqrtf(own);
            const float own_term = fmaf(-10.f, down, 25.f) + own;   // (5 - d_own)^2
            const float row_other = (25.f * K - 10.f * s1 + s2 - own_term) * (1.f / (K - 1));
            atomicAdd(&s_attr[li], own);
            atomicAdd(&s_rep[li], row_other);
            atomicAdd(&s_cnt[li], 1);
        }
    }

    __syncthreads();
    if (tid < K) {
        atomicAdd(&g_attr[tid], s_attr[tid]);
        atomicAdd(&g_rep[tid], s_rep[tid]);
        atomicAdd(&g_cnt[tid], s_cnt[tid]);
    }
}

__global__ void dcl_finish(const float* __restrict__ g_attr,
                           const float* __restrict__ g_rep,
                           const int*   __restrict__ g_cnt,
                           float* __restrict__ out)
{
    const int k = threadIdx.x;  // 64 threads = 1 wave
    const float cnt = (float)g_cnt[k];
    float v = (cnt > 0.f) ? (g_attr[k] + g_rep[k]) / cnt : 0.f;
    #pragma unroll
    for (int off = 32; off > 0; off >>= 1) v += __shfl_down(v, off);
    if (k == 0) out[0] = v * (1.f / K);
}

extern "C" void kernel_launch(void* const* d_in, const int* in_sizes, int n_in,
                              void* d_out, int out_size, void* d_ws, size_t ws_size,
                              hipStream_t stream) {
    const float* emb    = (const float*)d_in[0];
    const int*   labels = (const int*)d_in[1];
    const float* cent   = (const float*)d_in[2];
    float* out = (float*)d_out;

    float* g_attr = (float*)d_ws;
    float* g_rep  = g_attr + K;
    int*   g_cnt  = (int*)(g_rep + K);

    hipMemsetAsync(d_ws, 0, 3 * K * sizeof(float), stream);
    dcl_main<<<GRID, 256, 0, stream>>>(emb, labels, cent, g_attr, g_rep, g_cnt);
    dcl_finish<<<1, 64, 0, stream>>>(g_attr, g_rep, g_cnt, out);
}

// Round 6
// 209.915 us; speedup vs baseline: 1.1221x; 1.1221x over previous
//
#include <hip/hip_runtime.h>

// DistanceCentroidLoss, round 6: one 32-point tile per wave (no loop, no prefetch
// to sink), GRID=2048. Loads issue at wave start, overlap with sA staging.
// A=centroids (64 rows, 2 accumulators), B=points (32 cols/wave).
// d2 = x2 - 2*acc', acc' = dot - c2/2 (C initialized to -c2/2 via LDS tables).
// C/D layout (32x32x16): col = lane&31 (point), row = (reg&3) + 8*(reg>>2) + 4*(lane>>5).
// Panel stride 34 slots (272 B/row): writes 2 dw/bank (free), reads 8 dw/bank (min),
// 16B-aligned for all lanes (272 = 17*16).

constexpr int N = 262144;
constexpr int D = 128;
constexpr int K = 64;

constexpr int GRID = 2048;                   // 8192 tiles / 4 waves per block
constexpr int PANEL = 34 * 32;               // bf16x4 slots per wave panel

typedef __bf16 bf16x4 __attribute__((ext_vector_type(4)));
typedef __bf16 bf16x8 __attribute__((ext_vector_type(8)));
typedef float  f32x16 __attribute__((ext_vector_type(16)));

__global__ __launch_bounds__(256) void dcl_main(
    const float* __restrict__ emb,
    const int*   __restrict__ labels,
    const float* __restrict__ cent,
    float* __restrict__ g_attr,
    float* __restrict__ g_rep,
    int*   __restrict__ g_cnt)
{
    __shared__ bf16x8 sA[2 * 8 * 64];                    // 16 KB A-fragments
    __shared__ __align__(16) bf16x4 sPanel[4 * PANEL];   // 34 KB transpose panels
    __shared__ float  s_c2[K];
    __shared__ __align__(16) float sC2i0[2][16];         // -c2/2 acc0 init, [h][r]
    __shared__ __align__(16) float sC2i1[2][16];         // -c2/2 acc1 init, [h][r]
    __shared__ float  s_attr[K];
    __shared__ float  s_rep[K];
    __shared__ int    s_cnt[K];

    const int tid  = threadIdx.x;
    const int wave = tid >> 6;
    const int lane = tid & 63;
    const int l31  = lane & 31;
    const int h    = lane >> 5;

    const int tile = blockIdx.x * 4 + wave;   // one tile per wave

    // issue this wave's 16 KB immediately (contiguous: lane strides 16 B, 1 KB/inst)
    float4 buf[16];
    {
        const float4* src = (const float4*)emb + (size_t)tile * 1024 + lane;
        #pragma unroll
        for (int q = 0; q < 16; ++q) buf[q] = src[q * 64];
    }
    const int lbl = labels[tile * 32 + l31];

    // --- stage centroid A-fragments into LDS while tile loads fly ---
    #pragma unroll
    for (int e = tid; e < 2 * 8 * 64; e += 256) {
        const int t = e >> 9, s = (e >> 6) & 7, l = e & 63;
        const int c  = t * 32 + (l & 31);
        const int d0 = 16 * s + 8 * (l >> 5);
        const float4 f0 = *(const float4*)(cent + c * D + d0);
        const float4 f1 = *(const float4*)(cent + c * D + d0 + 4);
        bf16x8 v;
        v[0] = (__bf16)f0.x; v[1] = (__bf16)f0.y; v[2] = (__bf16)f0.z; v[3] = (__bf16)f0.w;
        v[4] = (__bf16)f1.x; v[5] = (__bf16)f1.y; v[6] = (__bf16)f1.z; v[7] = (__bf16)f1.w;
        sA[e] = v;
    }
    if (tid < K) {
        const float4* cp = (const float4*)(cent + tid * D);
        float sa = 0.f, sb = 0.f;
        #pragma unroll
        for (int q = 0; q < D / 8; ++q) {
            const float4 f = cp[2 * q];
            const float4 g = cp[2 * q + 1];
            sa = fmaf(f.x, f.x, sa); sa = fmaf(f.y, f.y, sa);
            sa = fmaf(f.z, f.z, sa); sa = fmaf(f.w, f.w, sa);
            sb = fmaf(g.x, g.x, sb); sb = fmaf(g.y, g.y, sb);
            sb = fmaf(g.z, g.z, sb); sb = fmaf(g.w, g.w, sb);
        }
        s_c2[tid] = sa + sb;
        s_attr[tid] = 0.f; s_rep[tid] = 0.f; s_cnt[tid] = 0;
    }
    __syncthreads();
    if (tid < 32) {
        const int hh = tid >> 4, r = tid & 15;
        const int rb = (r & 3) + 8 * (r >> 2) + 4 * hh;
        sC2i0[hh][r] = -0.5f * s_c2[rb];
        sC2i1[hh][r] = -0.5f * s_c2[rb + 32];
    }
    __syncthreads();

    bf16x4* panel = sPanel + wave * PANEL;

    // convert tile to bf16, transpose into panel (wave-private, no barrier needed)
    #pragma unroll
    for (int q = 0; q < 16; ++q) {
        bf16x4 v;
        v[0] = (__bf16)buf[q].x; v[1] = (__bf16)buf[q].y;
        v[2] = (__bf16)buf[q].z; v[3] = (__bf16)buf[q].w;
        const int n = 2 * q + h;            // point within tile
        panel[34 * n + l31] = v;            // chunk c = l31
    }

    // accumulators pre-initialized to -c2/2 (folds c2 into the GEMM)
    f32x16 acc0, acc1;
    {
        const float4* p0 = (const float4*)&sC2i0[h][0];
        const float4* p1 = (const float4*)&sC2i1[h][0];
        #pragma unroll
        for (int w = 0; w < 4; ++w) {
            ((float4*)&acc0)[w] = p0[w];
            ((float4*)&acc1)[w] = p1[w];
        }
    }

    float x2A = 0.f, x2B = 0.f;
    #pragma unroll
    for (int s = 0; s < 8; ++s) {
        const bf16x8 b = *(const bf16x8*)&panel[34 * l31 + 4 * s + 2 * h];
        // x2 partial sums with parallel chains (fmaf can't be reassociated)
        {
            const float e0 = (float)b[0], e1 = (float)b[1], e2 = (float)b[2], e3 = (float)b[3];
            const float e4 = (float)b[4], e5 = (float)b[5], e6 = (float)b[6], e7 = (float)b[7];
            float p0 = e0 * e0; p0 = fmaf(e1, e1, p0); p0 = fmaf(e2, e2, p0); p0 = fmaf(e3, e3, p0);
            float p1 = e4 * e4; p1 = fmaf(e5, e5, p1); p1 = fmaf(e6, e6, p1); p1 = fmaf(e7, e7, p1);
            x2A += p0; x2B += p1;
        }
        const bf16x8 a0 = sA[s * 64 + lane];
        const bf16x8 a1 = sA[(8 + s) * 64 + lane];
        acc0 = __builtin_amdgcn_mfma_f32_32x32x16_bf16(a0, b, acc0, 0, 0, 0);
        acc1 = __builtin_amdgcn_mfma_f32_32x32x16_bf16(a1, b, acc1, 0, 0, 0);
    }

    const float x2p = x2A + x2B;
    const float x2 = x2p + __shfl_xor(x2p, 32);

    // epilogue with parallel partial chains
    float s1a = 0.f, s1b = 0.f, s2a = 0.f, s2b = 0.f, own = 0.f;
    #pragma unroll
    for (int r = 0; r < 16; ++r) {
        const int rbase = (r & 3) + 8 * (r >> 2) + 4 * h;
        {
            float d2 = fmaf(-2.f, acc0[r], x2);
            d2 = fmaxf(d2, 0.f);
            const float dd = __builtin_amdgcn_sqrtf(d2);
            s1a += dd; s2a += d2;
            if (rbase == lbl) own += d2;
        }
        {
            float d2 = fmaf(-2.f, acc1[r], x2);
            d2 = fmaxf(d2, 0.f);
            const float dd = __builtin_amdgcn_sqrtf(d2);
            s1b += dd; s2b += d2;
            if (rbase + 32 == lbl) own += d2;
        }
    }
    float s1 = s1a + s1b, s2 = s2a + s2b;
    s1  += __shfl_xor(s1, 32);
    s2  += __shfl_xor(s2, 32);
    own += __shfl_xor(own, 32);

    if (lane < 32) {
        const float down = __builtin_amdgcn_sqrtf(own);
        const float own_term = fmaf(-10.f, down, 25.f) + own;   // (5 - d_own)^2
        const float row_other = (25.f * K - 10.f * s1 + s2 - own_term) * (1.f / (K - 1));
        atomicAdd(&s_attr[lbl], own);
        atomicAdd(&s_rep[lbl], row_other);
        atomicAdd(&s_cnt[lbl], 1);
    }

    __syncthreads();
    if (tid < K) {
        const int rep8 = (blockIdx.x & 7) * K;   // spread contention 8-way
        atomicAdd(&g_attr[rep8 + tid], s_attr[tid]);
        atomicAdd(&g_rep[rep8 + tid], s_rep[tid]);
        atomicAdd(&g_cnt[rep8 + tid], s_cnt[tid]);
    }
}

__global__ void dcl_finish(const float* __restrict__ g_attr,
                           const float* __restrict__ g_rep,
                           const int*   __restrict__ g_cnt,
                           float* __restrict__ out)
{
    const int k = threadIdx.x;  // 64 threads = 1 wave
    float a = 0.f, r = 0.f;
    int   c = 0;
    #pragma unroll
    for (int j = 0; j < 8; ++j) {
        a += g_attr[j * K + k];
        r += g_rep[j * K + k];
        c += g_cnt[j * K + k];
    }
    float v = (c > 0) ? (a + r) / (float)c : 0.f;
    #pragma unroll
    for (int off = 32; off > 0; off >>= 1) v += __shfl_down(v, off);
    if (k == 0) out[0] = v * (1.f / K);
}

extern "C" void kernel_launch(void* const* d_in, const int* in_sizes, int n_in,
                              void* d_out, int out_size, void* d_ws, size_t ws_size,
                              hipStream_t stream) {
    const float* emb    = (const float*)d_in[0];
    const int*   labels = (const int*)d_in[1];
    const float* cent   = (const float*)d_in[2];
    float* out = (float*)d_out;

    float* g_attr = (float*)d_ws;                 // [8][64]
    float* g_rep  = g_attr + 8 * K;               // [8][64]
    int*   g_cnt  = (int*)(g_rep + 8 * K);        // [8][64]

    hipMemsetAsync(d_ws, 0, 3 * 8 * K * sizeof(float), stream);
    dcl_main<<<GRID, 256, 0, stream>>>(emb, labels, cent, g_attr, g_rep, g_cnt);
    dcl_finish<<<1, 64, 0, stream>>>(g_attr, g_rep, g_cnt, out);
}

// Round 7
// 199.273 us; speedup vs baseline: 1.1820x; 1.0534x over previous
//
#include <hip/hip_runtime.h>

// DistanceCentroidLoss, round 7: per-wave 4-tile loop with register ping-pong
// pipeline. Loads for tile t+1 issue right after tile t's transpose, pinned by a
// sched_barrier so they stay in flight across the whole MFMA+epilogue phase.
// GRID=512 -> 2 blocks/CU resident (VGPR-bound at 2 waves/SIMD), zero tail.
// A=centroids (64 rows, 2 accumulators), B=points (32 cols/wave).
// d2 = x2 - 2*acc', acc' = dot - c2/2 (C initialized to -c2/2 via LDS tables).
// C/D layout (32x32x16): col = lane&31 (point), row = (reg&3) + 8*(reg>>2) + 4*(lane>>5).

constexpr int N = 262144;
constexpr int D = 128;
constexpr int K = 64;

constexpr int GRID = 512;
constexpr int TPW  = 4;                      // 8192 tiles / (512*4 waves)
constexpr int PANEL = 34 * 32;               // bf16x4 slots per wave panel

typedef __bf16 bf16x4 __attribute__((ext_vector_type(4)));
typedef __bf16 bf16x8 __attribute__((ext_vector_type(8)));
typedef float  f32x16 __attribute__((ext_vector_type(16)));

__global__ __launch_bounds__(256, 2) void dcl_main(
    const float* __restrict__ emb,
    const int*   __restrict__ labels,
    const float* __restrict__ cent,
    float* __restrict__ g_attr,
    float* __restrict__ g_rep,
    int*   __restrict__ g_cnt)
{
    __shared__ bf16x8 sA[2 * 8 * 64];                    // 16 KB A-fragments
    __shared__ __align__(16) bf16x4 sPanel[4 * PANEL];   // 34 KB transpose panels
    __shared__ float  s_c2[K];
    __shared__ __align__(16) float sC2i0[2][16];         // -c2/2 acc0 init, [h][r]
    __shared__ __align__(16) float sC2i1[2][16];         // -c2/2 acc1 init, [h][r]
    __shared__ float  s_attr[K];
    __shared__ float  s_rep[K];
    __shared__ int    s_cnt[K];

    const int tid  = threadIdx.x;
    const int wave = tid >> 6;
    const int lane = tid & 63;
    const int l31  = lane & 31;
    const int h    = lane >> 5;

    const int g     = blockIdx.x * 4 + wave;
    const int base  = g * TPW;                // 4 consecutive tiles per wave

    // issue tile 0 into bufA immediately (contiguous: lane strides 16 B)
    float4 bufA[16], bufB[16];
    {
        const float4* src = (const float4*)emb + (size_t)base * 1024 + lane;
        #pragma unroll
        for (int q = 0; q < 16; ++q) bufA[q] = src[q * 64];
    }
    int lbl[TPW];
    #pragma unroll
    for (int t = 0; t < TPW; ++t) lbl[t] = labels[(base + t) * 32 + l31];

    // --- stage centroid A-fragments into LDS while tile-0 loads fly ---
    #pragma unroll
    for (int e = tid; e < 2 * 8 * 64; e += 256) {
        const int t = e >> 9, s = (e >> 6) & 7, l = e & 63;
        const int c  = t * 32 + (l & 31);
        const int d0 = 16 * s + 8 * (l >> 5);
        const float4 f0 = *(const float4*)(cent + c * D + d0);
        const float4 f1 = *(const float4*)(cent + c * D + d0 + 4);
        bf16x8 v;
        v[0] = (__bf16)f0.x; v[1] = (__bf16)f0.y; v[2] = (__bf16)f0.z; v[3] = (__bf16)f0.w;
        v[4] = (__bf16)f1.x; v[5] = (__bf16)f1.y; v[6] = (__bf16)f1.z; v[7] = (__bf16)f1.w;
        sA[e] = v;
    }
    if (tid < K) {
        const float4* cp = (const float4*)(cent + tid * D);
        float sa = 0.f, sb = 0.f;
        #pragma unroll
        for (int q = 0; q < D / 8; ++q) {
            const float4 f = cp[2 * q];
            const float4 gg = cp[2 * q + 1];
            sa = fmaf(f.x, f.x, sa); sa = fmaf(f.y, f.y, sa);
            sa = fmaf(f.z, f.z, sa); sa = fmaf(f.w, f.w, sa);
            sb = fmaf(gg.x, gg.x, sb); sb = fmaf(gg.y, gg.y, sb);
            sb = fmaf(gg.z, gg.z, sb); sb = fmaf(gg.w, gg.w, sb);
        }
        s_c2[tid] = sa + sb;
        s_attr[tid] = 0.f; s_rep[tid] = 0.f; s_cnt[tid] = 0;
    }
    __syncthreads();
    if (tid < 32) {
        const int hh = tid >> 4, r = tid & 15;
        const int rb = (r & 3) + 8 * (r >> 2) + 4 * hh;
        sC2i0[hh][r] = -0.5f * s_c2[rb];
        sC2i1[hh][r] = -0.5f * s_c2[rb + 32];
    }
    __syncthreads();

    bf16x4* panel = sPanel + wave * PANEL;

    #pragma unroll
    for (int t = 0; t < TPW; ++t) {
        float4* cur = (t & 1) ? bufB : bufA;
        float4* nxt = (t & 1) ? bufA : bufB;

        // transpose current tile to panel (consumes cur -> frees it for t+2)
        #pragma unroll
        for (int q = 0; q < 16; ++q) {
            bf16x4 v;
            v[0] = (__bf16)cur[q].x; v[1] = (__bf16)cur[q].y;
            v[2] = (__bf16)cur[q].z; v[3] = (__bf16)cur[q].w;
            const int n = 2 * q + h;
            panel[34 * n + l31] = v;
        }

        // issue next tile's loads NOW; pin the issue point so the whole
        // MFMA+epilogue phase runs with these in flight.
        if (t + 1 < TPW) {
            const float4* src = (const float4*)emb + (size_t)(base + t + 1) * 1024 + lane;
            #pragma unroll
            for (int q = 0; q < 16; ++q) nxt[q] = src[q * 64];
        }
        __builtin_amdgcn_sched_barrier(0);

        f32x16 acc0, acc1;
        {
            const float4* p0 = (const float4*)&sC2i0[h][0];
            const float4* p1 = (const float4*)&sC2i1[h][0];
            #pragma unroll
            for (int w = 0; w < 4; ++w) {
                ((float4*)&acc0)[w] = p0[w];
                ((float4*)&acc1)[w] = p1[w];
            }
        }

        float x2A = 0.f, x2B = 0.f;
        #pragma unroll
        for (int s = 0; s < 8; ++s) {
            const bf16x8 b = *(const bf16x8*)&panel[34 * l31 + 4 * s + 2 * h];
            {
                const float e0 = (float)b[0], e1 = (float)b[1], e2 = (float)b[2], e3 = (float)b[3];
                const float e4 = (float)b[4], e5 = (float)b[5], e6 = (float)b[6], e7 = (float)b[7];
                float p0 = e0 * e0; p0 = fmaf(e1, e1, p0); p0 = fmaf(e2, e2, p0); p0 = fmaf(e3, e3, p0);
                float p1 = e4 * e4; p1 = fmaf(e5, e5, p1); p1 = fmaf(e6, e6, p1); p1 = fmaf(e7, e7, p1);
                x2A += p0; x2B += p1;
            }
            const bf16x8 a0 = sA[s * 64 + lane];
            const bf16x8 a1 = sA[(8 + s) * 64 + lane];
            acc0 = __builtin_amdgcn_mfma_f32_32x32x16_bf16(a0, b, acc0, 0, 0, 0);
            acc1 = __builtin_amdgcn_mfma_f32_32x32x16_bf16(a1, b, acc1, 0, 0, 0);
        }

        const float x2p = x2A + x2B;
        const float x2 = x2p + __shfl_xor(x2p, 32);
        const int li = lbl[t];

        float s1a = 0.f, s1b = 0.f, s2a = 0.f, s2b = 0.f, own = 0.f;
        #pragma unroll
        for (int r = 0; r < 16; ++r) {
            const int rbase = (r & 3) + 8 * (r >> 2) + 4 * h;
            {
                float d2 = fmaf(-2.f, acc0[r], x2);
                d2 = fmaxf(d2, 0.f);
                const float dd = __builtin_amdgcn_sqrtf(d2);
                s1a += dd; s2a += d2;
                if (rbase == li) own += d2;
            }
            {
                float d2 = fmaf(-2.f, acc1[r], x2);
                d2 = fmaxf(d2, 0.f);
                const float dd = __builtin_amdgcn_sqrtf(d2);
                s1b += dd; s2b += d2;
                if (rbase + 32 == li) own += d2;
            }
        }
        float s1 = s1a + s1b, s2 = s2a + s2b;
        s1  += __shfl_xor(s1, 32);
        s2  += __shfl_xor(s2, 32);
        own += __shfl_xor(own, 32);

        if (lane < 32) {
            const float down = __builtin_amdgcn_sqrtf(own);
            const float own_term = fmaf(-10.f, down, 25.f) + own;   // (5 - d_own)^2
            const float row_other = (25.f * K - 10.f * s1 + s2 - own_term) * (1.f / (K - 1));
            atomicAdd(&s_attr[li], own);
            atomicAdd(&s_rep[li], row_other);
            atomicAdd(&s_cnt[li], 1);
        }
    }

    __syncthreads();
    if (tid < K) {
        const int rep8 = (blockIdx.x & 7) * K;   // spread contention 8-way
        atomicAdd(&g_attr[rep8 + tid], s_attr[tid]);
        atomicAdd(&g_rep[rep8 + tid], s_rep[tid]);
        atomicAdd(&g_cnt[rep8 + tid], s_cnt[tid]);
    }
}

__global__ void dcl_finish(const float* __restrict__ g_attr,
                           const float* __restrict__ g_rep,
                           const int*   __restrict__ g_cnt,
                           float* __restrict__ out)
{
    const int k = threadIdx.x;  // 64 threads = 1 wave
    float a = 0.f, r = 0.f;
    int   c = 0;
    #pragma unroll
    for (int j = 0; j < 8; ++j) {
        a += g_attr[j * K + k];
        r += g_rep[j * K + k];
        c += g_cnt[j * K + k];
    }
    float v = (c > 0) ? (a + r) / (float)c : 0.f;
    #pragma unroll
    for (int off = 32; off > 0; off >>= 1) v += __shfl_down(v, off);
    if (k == 0) out[0] = v * (1.f / K);
}

extern "C" void kernel_launch(void* const* d_in, const int* in_sizes, int n_in,
                              void* d_out, int out_size, void* d_ws, size_t ws_size,
                              hipStream_t stream) {
    const float* emb    = (const float*)d_in[0];
    const int*   labels = (const int*)d_in[1];
    const float* cent   = (const float*)d_in[2];
    float* out = (float*)d_out;

    float* g_attr = (float*)d_ws;                 // [8][64]
    float* g_rep  = g_attr + 8 * K;               // [8][64]
    int*   g_cnt  = (int*)(g_rep + 8 * K);        // [8][64]

    hipMemsetAsync(d_ws, 0, 3 * 8 * K * sizeof(float), stream);
    dcl_main<<<GRID, 256, 0, stream>>>(emb, labels, cent, g_attr, g_rep, g_cnt);
    dcl_finish<<<1, 64, 0, stream>>>(g_attr, g_rep, g_cnt, out);
}